// Round 1
// baseline (59.413 us; speedup 1.0000x reference)
//
#include <hip/hip_runtime.h>

#define S     4096
#define CIN   7
#define DM    512
#define KERN  73
#define TT    256           // time steps per block tile
#define TILES (S / TT)      // 16
#define TROW  276           // TT + 17 = 273, rounded up to multiple of 4 (16B align)
#define CHUNK 8

__global__ __launch_bounds__(512, 4)
void tokemb_kernel(const float* __restrict__ x,
                   const float* __restrict__ w_conv,
                   const float* __restrict__ b_conv,
                   const float* __restrict__ w_left,
                   const float* __restrict__ b_left,
                   float* __restrict__ out)
{
    __shared__ float xs[CIN * TROW];

    const int blk  = blockIdx.x;
    const int b    = blk / TILES;
    const int tile = blk - b * TILES;
    const int t0   = tile * TT;
    const int d    = threadIdx.x;

    // ---- stage x tile into LDS, transposed: xs[c][j], j in [0, TT+17) ----
    // xs[c][j] = x[b, (t0 - 16 + j) mod S, c]
    const int NE = CIN * (TT + 17);
    const float* xb = x + (long long)b * S * CIN;
    for (int e = d; e < NE; e += 512) {
        int j = e / CIN;            // magic-mul div by 7
        int c = e - j * CIN;
        int tm = t0 - 16 + j;
        if (tm < 0) tm += S;
        else if (tm >= S) tm -= S;
        xs[c * TROW + j] = xb[tm * CIN + c];
    }

    // ---- per-thread fixed weights (18 floats) ----
    const int cc = (d < DM - 1) ? (d / KERN) : (CIN - 1);
    const int oo = d % KERN;
    const float* wrow = (d < DM - 1) ? (w_conv + oo * 18) : w_left;
    const float bias  = (d < DM - 1) ? b_conv[oo] : b_left[0];
    float wt[18];
    #pragma unroll
    for (int q = 0; q < 18; ++q) wt[q] = wrow[q];

    __syncthreads();

    const float* xrow = xs + cc * TROW;
    float* op = out + ((long long)b * S + t0) * DM + d;

    for (int tt0 = 0; tt0 < TT; tt0 += CHUNK) {
        // sliding window for 8 consecutive t: j in [tt0, tt0+24] -> 7x float4
        float win[28];
        #pragma unroll
        for (int q = 0; q < 7; ++q) {
            float4 v = *reinterpret_cast<const float4*>(xrow + tt0 + 4 * q);
            win[4*q+0] = v.x; win[4*q+1] = v.y;
            win[4*q+2] = v.z; win[4*q+3] = v.w;
        }

        float acc[CHUNK];
        const int tc = t0 + tt0;
        const bool edge = (tc < 16) || (tc + CHUNK >= S);  // uniform branch
        if (!edge) {
            #pragma unroll
            for (int i = 0; i < CHUNK; ++i) {
                float a = bias;
                #pragma unroll
                for (int m = 0; m < 6; ++m) {
                    #pragma unroll
                    for (int k = 0; k < 3; ++k) {
                        a = fmaf(wt[m*3+k], win[i + k + 15 - 3*m], a);
                    }
                }
                acc[i] = a;
            }
        } else {
            #pragma unroll
            for (int i = 0; i < CHUNK; ++i) {
                float p0 = 0.f, p1 = 0.f, p2 = 0.f;
                #pragma unroll
                for (int m = 0; m < 6; ++m) {
                    p0 = fmaf(wt[m*3+0], win[i + 15 - 3*m], p0);
                    p1 = fmaf(wt[m*3+1], win[i + 16 - 3*m], p1);
                    p2 = fmaf(wt[m*3+2], win[i + 17 - 3*m], p2);
                }
                const int t = tc + i;
                const float f0 = (t == 0 || t >= 16)      ? 1.f : 0.f;
                const float f1 = (t >= 15)                ? 1.f : 0.f;
                const float f2 = (t >= 14 && t != S - 1)  ? 1.f : 0.f;
                acc[i] = bias + f0 * p0 + f1 * p1 + f2 * p2;
            }
        }

        #pragma unroll
        for (int i = 0; i < CHUNK; ++i) {
            __builtin_nontemporal_store(acc[i], op + (tt0 + i) * DM);
        }
    }
}

extern "C" void kernel_launch(void* const* d_in, const int* in_sizes, int n_in,
                              void* d_out, int out_size, void* d_ws, size_t ws_size,
                              hipStream_t stream) {
    const float* x      = (const float*)d_in[0];
    const float* w_conv = (const float*)d_in[1];
    const float* b_conv = (const float*)d_in[2];
    const float* w_left = (const float*)d_in[3];
    const float* b_left = (const float*)d_in[4];
    float* out = (float*)d_out;

    const int B = in_sizes[0] / (S * CIN);   // 32
    dim3 grid(B * TILES);
    tokemb_kernel<<<grid, 512, 0, stream>>>(x, w_conv, b_conv, w_left, b_left, out);
}